// Round 3
// baseline (132.155 us; speedup 1.0000x reference)
//
#include <hip/hip_runtime.h>
#include <math.h>

#define RESG 128
#define CHG 28
#define NT 767
#define NBKT 96

static __device__ __forceinline__ unsigned short f2bf(float x) {
    unsigned u = __float_as_uint(x);
    return (unsigned short)((u + 0x7FFFu + ((u >> 16) & 1u)) >> 16);
}
static __device__ __forceinline__ float bf2f(unsigned short h) {
    return __uint_as_float(((unsigned)h) << 16);
}

// ---------- prep: bucket rays by direction (cubemap face + 4x4) ----------
__global__ __launch_bounds__(1024) void prep_sort(
    const float* __restrict__ rays_d, int* __restrict__ perm, int B)
{
    __shared__ int cnt[NBKT];
    __shared__ int off[NBKT];
    __shared__ unsigned char keys[4096];
    const int tid = threadIdx.x;
    for (int i = tid; i < NBKT; i += 1024) cnt[i] = 0;
    __syncthreads();
    for (int r = tid; r < B; r += 1024) {
        float ddx = rays_d[r*3+0], ddy = rays_d[r*3+1], ddz = rays_d[r*3+2];
        float ax = fabsf(ddx), ay = fabsf(ddy), az = fabsf(ddz);
        int face; float u, v, m;
        if (ax >= ay && ax >= az) { face = (ddx < 0.f) ? 0 : 1; m = ax; u = ddy; v = ddz; }
        else if (ay >= az)        { face = (ddy < 0.f) ? 2 : 3; m = ay; u = ddx; v = ddz; }
        else                      { face = (ddz < 0.f) ? 4 : 5; m = az; u = ddx; v = ddy; }
        float iu = u / m * 0.5f + 0.5f;
        float iv = v / m * 0.5f + 0.5f;
        int qu = min(3, max(0, (int)(iu * 4.0f)));
        int qv = min(3, max(0, (int)(iv * 4.0f)));
        int k = face * 16 + qu * 4 + qv;
        keys[r] = (unsigned char)k;
        atomicAdd(&cnt[k], 1);
    }
    __syncthreads();
    if (tid == 0) {
        int a = 0;
        for (int i = 0; i < NBKT; ++i) { off[i] = a; a += cnt[i]; }
    }
    __syncthreads();
    for (int r = tid; r < B; r += 1024) {
        int k = keys[r];
        int slot = atomicAdd(&off[k], 1);
        perm[slot] = r;
    }
}

// ---------- main ----------
__global__ __launch_bounds__(256, 4) void nerf_grid_kernel(
    const float* __restrict__ rays_d,
    const float* __restrict__ rays_o,
    const float* __restrict__ grid,     // [128^3][28] f32, row = 112B
    const int*   __restrict__ perm,
    float* __restrict__ out_rgb,
    float* __restrict__ out_alpha,
    float* __restrict__ out_depth)
{
    const int ray  = perm[blockIdx.x];
    const int tid  = threadIdx.x;
    const int lane = tid & 63;
    const int wave = tid >> 6;

    const float EPSC   = 1e-10f;
    const float INV127 = 1.0f / 127.0f;

    __shared__ float stage[4][1792];          // 4 waves x 64 slots x 28 floats (112B)
    __shared__ float a_lds[NT + 1];
    __shared__ unsigned int   rg_lds[NT + 1]; // bf16 r | bf16 g
    __shared__ unsigned short b_lds[NT + 1];  // bf16 b
    __shared__ float wprod[4];
    __shared__ float red[4][5];

    // ---- per-ray setup ----
    const float ox = rays_o[ray*3+0], oy = rays_o[ray*3+1], oz = rays_o[ray*3+2];
    const float dx = rays_d[ray*3+0], dy = rays_d[ray*3+1], dz = rays_d[ray*3+2];
    const float dnorm = sqrtf(dx*dx + dy*dy + dz*dz);

    float txp = (1.0f - ox)/dx, txn = (-1.0f - ox)/dx;
    float typ = (1.0f - oy)/dy, tyn = (-1.0f - oy)/dy;
    float tzp = (1.0f - oz)/dz, tzn = (-1.0f - oz)/dz;
    const float start = fmaxf(fmaxf(fminf(txp,txn), fminf(typ,tyn)), fminf(tzp,tzn));
    const float stop  = fminf(fminf(fmaxf(txp,txn), fmaxf(typ,tyn)), fmaxf(tzp,tzn));

    int n_proc = (int)((stop - start) * 127.0f) + 2;
    n_proc = n_proc < 0 ? 0 : (n_proc > NT ? NT : n_proc);

    const float inv = 1.0f/dnorm;
    const float nx = dx*inv, ny = dy*inv, nz = dz*inv;
    float sh0, sh1, sh2, sh3, sh4, sh5, sh6, sh7, sh8;
    {
        const float C0 = 0.28209479177387814f;
        const float C1 = 0.4886025119029199f;
        const float C20 = 1.0925484305920792f, C21 = -1.0925484305920792f;
        const float C22 = 0.31539156525252005f;
        const float C23 = -1.0925484305920792f, C24 = 0.5462742152960396f;
        sh0 = C0;   sh1 = -C1*ny; sh2 = C1*nz; sh3 = -C1*nx;
        sh4 = C20*nx*ny; sh5 = C21*ny*nz;
        sh6 = C22*(2.0f*nz*nz - nx*nx - ny*ny);
        sh7 = C23*nx*nz; sh8 = C24*(nx*nx - ny*ny);
    }

    const int samp   = lane >> 3;   // 0..7
    const int corner = lane & 7;    // bit0=x, bit1=y, bit2=z
    const int cdx = corner & 1, cdy = (corner >> 1) & 1, cdz = corner >> 2;
    const char* gridc = (const char*)grid;

    // ---- phase 1: per-iteration: dense-stage 64 rows (8 samples x 8 corners) ----
    for (int base = 0; base < n_proc; base += 32) {
        const int s = base + wave*8 + samp;
        const float t0 = fminf(start + (float)(s+1)*INV127, stop);
        const float t1 = fminf(start + (float)(s+2)*INV127, stop);
        const float dist = (t1 - t0) * dnorm;
        const bool on = (s < n_proc) && (dist > 0.0f);

        const float gx = (ox + t0*dx + 1.0f)*63.5f;
        const float gy = (oy + t0*dy + 1.0f)*63.5f;
        const float gz = (oz + t0*dz + 1.0f)*63.5f;
        const float fx0 = floorf(gx), fy0 = floorf(gy), fz0 = floorf(gz);
        const float fx = gx - fx0, fy = gy - fy0, fz = gz - fz0;
        const int ix = (int)fx0 + cdx;
        const int iy = (int)fy0 + cdy;
        const int iz = (int)fz0 + cdz;
        const bool valid = on & ((unsigned)ix < (unsigned)RESG)
                              & ((unsigned)iy < (unsigned)RESG)
                              & ((unsigned)iz < (unsigned)RESG);
        const int xc = min(RESG-1, max(0, ix));
        const int yc = min(RESG-1, max(0, iy));
        const int zc = min(RESG-1, max(0, iz));
        const unsigned gb = (unsigned)(((zc*RESG + yc)*RESG + xc) * 112);
        const float w = valid ? (cdx ? fx : 1.0f-fx) *
                                (cdy ? fy : 1.0f-fy) *
                                (cdz ? fz : 1.0f-fz) : 0.0f;

        // dense load: g = i*64+lane -> slot=g/7, chunk=g%7 (full 112B rows contiguous)
        #pragma unroll
        for (int i = 0; i < 7; ++i) {
            const int g = i*64 + lane;
            const int slot = (g * 18725) >> 17;          // g/7 exact for g<448
            const int ch   = g - slot*7;
            const unsigned gbv = (unsigned)__shfl((int)gb, slot, 64);
            const float4 v = *(const float4*)(gridc + (size_t)gbv + (size_t)(ch << 4));
            const int rs  = ch + slot;
            const int rot = rs - 7*((rs * 18725) >> 17); // (ch+slot)%7 bank swizzle
            *(float4*)(&stage[wave][slot*28 + rot*4]) = v;
        }
        __syncthreads();

        // consume own slot (lane == slot)
        float4 c0, c1, c2, c3, c4, c5, c6;
        {
            int rs, rot;
            rs = 0 + lane; rot = rs - 7*((rs*18725)>>17); c0 = *(const float4*)(&stage[wave][lane*28 + rot*4]);
            rs = 1 + lane; rot = rs - 7*((rs*18725)>>17); c1 = *(const float4*)(&stage[wave][lane*28 + rot*4]);
            rs = 2 + lane; rot = rs - 7*((rs*18725)>>17); c2 = *(const float4*)(&stage[wave][lane*28 + rot*4]);
            rs = 3 + lane; rot = rs - 7*((rs*18725)>>17); c3 = *(const float4*)(&stage[wave][lane*28 + rot*4]);
            rs = 4 + lane; rot = rs - 7*((rs*18725)>>17); c4 = *(const float4*)(&stage[wave][lane*28 + rot*4]);
            rs = 5 + lane; rot = rs - 7*((rs*18725)>>17); c5 = *(const float4*)(&stage[wave][lane*28 + rot*4]);
            rs = 6 + lane; rot = rs - 7*((rs*18725)>>17); c6 = *(const float4*)(&stage[wave][lane*28 + rot*4]);
        }
        float rr = w*(c0.x*sh0 + c0.y*sh1 + c0.z*sh2 + c0.w*sh3 +
                      c1.x*sh4 + c1.y*sh5 + c1.z*sh6 + c1.w*sh7 + c2.x*sh8);
        float gg = w*(c2.y*sh0 + c2.z*sh1 + c2.w*sh2 + c3.x*sh3 +
                      c3.y*sh4 + c3.z*sh5 + c3.w*sh6 + c4.x*sh7 + c4.y*sh8);
        float bb = w*(c4.z*sh0 + c4.w*sh1 + c5.x*sh2 + c5.y*sh3 +
                      c5.z*sh4 + c5.w*sh5 + c6.x*sh6 + c6.y*sh7 + c6.z*sh8);
        float sg = w*c6.w;

        #pragma unroll
        for (int off2 = 1; off2 < 8; off2 <<= 1) {
            rr += __shfl_xor(rr, off2, 64);
            gg += __shfl_xor(gg, off2, 64);
            bb += __shfl_xor(bb, off2, 64);
            sg += __shfl_xor(sg, off2, 64);
        }
        if (s < n_proc) {
            if (corner == 0) {
                a_lds[s] = 1.0f - expf(-fmaxf(sg, 0.0f)*dist);
            } else if (corner == 1) {
                const float r1 = 1.0f/(1.0f + expf(-rr));
                const float g1 = 1.0f/(1.0f + expf(-gg));
                rg_lds[s] = ((unsigned)f2bf(r1) << 16) | (unsigned)f2bf(g1);
            } else if (corner == 2) {
                b_lds[s] = f2bf(1.0f/(1.0f + expf(-bb)));
            }
        }
        __syncthreads();
    }
    __syncthreads();

    // coalesced alpha output (zeros for dead range)
    for (int s = tid; s < NT; s += 256)
        out_alpha[(size_t)ray*NT + s] = (s < n_proc) ? a_lds[s] : 0.0f;

    // ---- phase 2: per-thread 3 consecutive samples ----
    float a_r[3], q_r[3], t_r[3], rr_r[3], gg_r[3], bb_r[3];
    #pragma unroll
    for (int k = 0; k < 3; ++k) {
        const int s = tid*3 + k;
        float a = 0.0f, rr = 0.0f, gg = 0.0f, bb = 0.0f, tt = 0.0f;
        if (s < NT) {
            tt = fminf(start + (float)(s+1)*INV127, stop);
            if (s < n_proc) {
                a = a_lds[s];
                const unsigned rg = rg_lds[s];
                rr = bf2f((unsigned short)(rg >> 16));
                gg = bf2f((unsigned short)(rg & 0xFFFFu));
                bb = bf2f(b_lds[s]);
            }
        }
        a_r[k] = a; q_r[k] = (s < NT) ? (1.0f - a + EPSC) : 1.0f;
        t_r[k] = tt; rr_r[k] = rr; gg_r[k] = gg; bb_r[k] = bb;
    }

    // ---- block-wide exclusive product scan ----
    const float P = q_r[0]*q_r[1]*q_r[2];
    float incl = P;
    #pragma unroll
    for (int off2 = 1; off2 < 64; off2 <<= 1) {
        const float n = __shfl_up(incl, off2, 64);
        if (lane >= off2) incl *= n;
    }
    float excl = __shfl_up(incl, 1, 64);
    if (lane == 0) excl = 1.0f;

    if (lane == 63) wprod[wave] = incl;
    __syncthreads();
    float wpre = 1.0f;
    for (int w2 = 0; w2 < 4; ++w2) if (w2 < wave) wpre *= wprod[w2];

    // ---- phase 3: weighted accumulation ----
    float cum = wpre * excl;
    float accA = 0.0f, accR = 0.0f, accG = 0.0f, accB = 0.0f, accD = 0.0f;
    #pragma unroll
    for (int k = 0; k < 3; ++k) {
        const float abs_l = a_r[k] * cum;
        accA += abs_l;
        accR += abs_l * rr_r[k];
        accG += abs_l * gg_r[k];
        accB += abs_l * bb_r[k];
        accD += abs_l * t_r[k];
        cum *= q_r[k];
    }

    #pragma unroll
    for (int off2 = 32; off2 > 0; off2 >>= 1) {
        accA += __shfl_down(accA, off2, 64);
        accR += __shfl_down(accR, off2, 64);
        accG += __shfl_down(accG, off2, 64);
        accB += __shfl_down(accB, off2, 64);
        accD += __shfl_down(accD, off2, 64);
    }
    if (lane == 0) {
        red[wave][0] = accA; red[wave][1] = accR; red[wave][2] = accG;
        red[wave][3] = accB; red[wave][4] = accD;
    }
    __syncthreads();
    if (tid == 0) {
        float A = 0.0f, R = 0.0f, G = 0.0f, Bv = 0.0f, D = 0.0f;
        #pragma unroll
        for (int w2 = 0; w2 < 4; ++w2) {
            A += red[w2][0]; R += red[w2][1]; G += red[w2][2];
            Bv += red[w2][3]; D += red[w2][4];
        }
        const float bg = 1.0f - A;
        out_rgb[ray*3+0] = R  + bg;
        out_rgb[ray*3+1] = G  + bg;
        out_rgb[ray*3+2] = Bv + bg;
        out_depth[ray] = D;
    }
}

extern "C" void kernel_launch(void* const* d_in, const int* in_sizes, int n_in,
                              void* d_out, int out_size, void* d_ws, size_t ws_size,
                              hipStream_t stream) {
    const float* rays_d = (const float*)d_in[0];
    const float* rays_o = (const float*)d_in[1];
    const float* grid   = (const float*)d_in[2];
    const int B = in_sizes[0] / 3;   // 4096

    float* out       = (float*)d_out;
    float* out_rgb   = out;
    float* out_alpha = out + (size_t)B*3;
    float* out_depth = out + (size_t)B*3 + (size_t)B*NT;

    int* perm = (int*)d_ws;

    prep_sort<<<1, 1024, 0, stream>>>(rays_d, perm, B);
    nerf_grid_kernel<<<B, 256, 0, stream>>>(rays_d, rays_o, grid, perm,
                                            out_rgb, out_alpha, out_depth);
}

// Round 4
// 89.347 us; speedup vs baseline: 1.4791x; 1.4791x over previous
//
#include <hip/hip_runtime.h>
#include <math.h>

#define RESG 128
#define CHG 28
#define NT 767
#define NBKT 384   // 6 faces x 8x8

// ---------- prep: bucket rays by direction (cubemap face + 8x8) ----------
__global__ __launch_bounds__(1024) void prep_sort(
    const float* __restrict__ rays_d, int* __restrict__ perm, int B)
{
    __shared__ int cnt[NBKT];
    __shared__ int off[NBKT];
    __shared__ unsigned short keys[4096];
    const int tid = threadIdx.x;
    for (int i = tid; i < NBKT; i += 1024) cnt[i] = 0;
    __syncthreads();
    for (int r = tid; r < B; r += 1024) {
        float ddx = rays_d[r*3+0], ddy = rays_d[r*3+1], ddz = rays_d[r*3+2];
        float ax = fabsf(ddx), ay = fabsf(ddy), az = fabsf(ddz);
        int face; float u, v, m;
        if (ax >= ay && ax >= az) { face = (ddx < 0.f) ? 0 : 1; m = ax; u = ddy; v = ddz; }
        else if (ay >= az)        { face = (ddy < 0.f) ? 2 : 3; m = ay; u = ddx; v = ddz; }
        else                      { face = (ddz < 0.f) ? 4 : 5; m = az; u = ddx; v = ddy; }
        float iu = u / m * 0.5f + 0.5f;
        float iv = v / m * 0.5f + 0.5f;
        int qu = min(7, max(0, (int)(iu * 8.0f)));
        int qv = min(7, max(0, (int)(iv * 8.0f)));
        int k = face * 64 + qu * 8 + qv;
        keys[r] = (unsigned short)k;
        atomicAdd(&cnt[k], 1);
    }
    __syncthreads();
    if (tid == 0) {
        int a = 0;
        for (int i = 0; i < NBKT; ++i) { off[i] = a; a += cnt[i]; }
    }
    __syncthreads();
    for (int r = tid; r < B; r += 1024) {
        int k = keys[r];
        int slot = atomicAdd(&off[k], 1);
        perm[slot] = r;
    }
}

// ---------- main ----------
__global__ __launch_bounds__(256) void nerf_grid_kernel(
    const float* __restrict__ rays_d,
    const float* __restrict__ rays_o,
    const float* __restrict__ grid,     // [128^3][28] f32
    const int*   __restrict__ perm,
    float* __restrict__ out_rgb,
    float* __restrict__ out_alpha,
    float* __restrict__ out_depth)
{
    const int ray  = perm[blockIdx.x];
    const int tid  = threadIdx.x;
    const int lane = tid & 63;
    const int wave = tid >> 6;

    const float EPSC   = 1e-10f;
    const float INV127 = 1.0f / 127.0f;

    __shared__ float a_lds[NT + 1];
    __shared__ float r_lds[NT + 1];
    __shared__ float g_lds[NT + 1];
    __shared__ float b_lds[NT + 1];
    __shared__ float wprod[4];
    __shared__ float red[4][5];

    // ---- per-ray setup ----
    const float ox = rays_o[ray*3+0], oy = rays_o[ray*3+1], oz = rays_o[ray*3+2];
    const float dx = rays_d[ray*3+0], dy = rays_d[ray*3+1], dz = rays_d[ray*3+2];
    const float dnorm = sqrtf(dx*dx + dy*dy + dz*dz);

    float txp = (1.0f - ox)/dx, txn = (-1.0f - ox)/dx;
    float typ = (1.0f - oy)/dy, tyn = (-1.0f - oy)/dy;
    float tzp = (1.0f - oz)/dz, tzn = (-1.0f - oz)/dz;
    const float start = fmaxf(fmaxf(fminf(txp,txn), fminf(typ,tyn)), fminf(tzp,tzn));
    const float stop  = fminf(fminf(fmaxf(txp,txn), fmaxf(typ,tyn)), fmaxf(tzp,tzn));

    // conservative live-sample count
    int n_proc = (int)((stop - start) * 127.0f) + 2;
    n_proc = n_proc < 0 ? 0 : (n_proc > NT ? NT : n_proc);

    // SH deg-2 basis
    const float inv = 1.0f/dnorm;
    const float nx = dx*inv, ny = dy*inv, nz = dz*inv;
    float sh0, sh1, sh2, sh3, sh4, sh5, sh6, sh7, sh8;
    {
        const float C0 = 0.28209479177387814f;
        const float C1 = 0.4886025119029199f;
        const float C20 = 1.0925484305920792f, C21 = -1.0925484305920792f;
        const float C22 = 0.31539156525252005f;
        const float C23 = -1.0925484305920792f, C24 = 0.5462742152960396f;
        sh0 = C0;   sh1 = -C1*ny; sh2 = C1*nz; sh3 = -C1*nx;
        sh4 = C20*nx*ny; sh5 = C21*ny*nz;
        sh6 = C22*(2.0f*nz*nz - nx*nx - ny*ny);
        sh7 = C23*nx*nz; sh8 = C24*(nx*nx - ny*ny);
    }

    // ---- phase 1: lane-per-corner gather; wave handles 8 consecutive samples ----
    const int samp   = lane >> 3;     // 0..7
    const int corner = lane & 7;      // bit0=dx, bit1=dy, bit2=dz
    const int cdx = corner & 1, cdy = (corner >> 1) & 1, cdz = corner >> 2;

    for (int base = wave*8; base < n_proc; base += 32) {
        const int s = base + samp;
        float rr = 0.0f, gg = 0.0f, bb = 0.0f, sg = 0.0f;
        float t0 = 0.0f, dist = 0.0f;
        bool live = false;
        if (s < n_proc) {
            t0 = fminf(start + (float)(s+1)*INV127, stop);
            const float t1 = fminf(start + (float)(s+2)*INV127, stop);
            dist = (t1 - t0) * dnorm;
            live = dist > 0.0f;
        }
        if (live) {
            const float gx = (ox + t0*dx + 1.0f)*63.5f;
            const float gy = (oy + t0*dy + 1.0f)*63.5f;
            const float gz = (oz + t0*dz + 1.0f)*63.5f;
            const float fx0 = floorf(gx), fy0 = floorf(gy), fz0 = floorf(gz);
            const float fx = gx - fx0, fy = gy - fy0, fz = gz - fz0;
            const int xi = (int)fx0 + cdx;
            const int yi = (int)fy0 + cdy;
            const int zi = (int)fz0 + cdz;
            const bool valid = ((unsigned)xi < (unsigned)RESG) &
                               ((unsigned)yi < (unsigned)RESG) &
                               ((unsigned)zi < (unsigned)RESG);
            const float w = (cdx ? fx : 1.0f-fx) *
                            (cdy ? fy : 1.0f-fy) *
                            (cdz ? fz : 1.0f-fz);
            if (valid && w != 0.0f) {
                const float4* row = (const float4*)(grid + (size_t)(((zi*RESG) + yi)*RESG + xi)*CHG);
                const float4 v0 = row[0], v1 = row[1], v2 = row[2], v3 = row[3];
                const float4 v4 = row[4], v5 = row[5], v6 = row[6];
                rr = w*(v0.x*sh0 + v0.y*sh1 + v0.z*sh2 + v0.w*sh3 +
                        v1.x*sh4 + v1.y*sh5 + v1.z*sh6 + v1.w*sh7 + v2.x*sh8);
                gg = w*(v2.y*sh0 + v2.z*sh1 + v2.w*sh2 + v3.x*sh3 +
                        v3.y*sh4 + v3.z*sh5 + v3.w*sh6 + v4.x*sh7 + v4.y*sh8);
                bb = w*(v4.z*sh0 + v4.w*sh1 + v5.x*sh2 + v5.y*sh3 +
                        v5.z*sh4 + v5.w*sh5 + v6.x*sh6 + v6.y*sh7 + v6.z*sh8);
                sg = w*v6.w;
            }
        }
        #pragma unroll
        for (int off2 = 1; off2 < 8; off2 <<= 1) {
            rr += __shfl_xor(rr, off2, 64);
            gg += __shfl_xor(gg, off2, 64);
            bb += __shfl_xor(bb, off2, 64);
            sg += __shfl_xor(sg, off2, 64);
        }
        if (corner == 0 && s < n_proc) {
            a_lds[s] = live ? 1.0f - expf(-fmaxf(sg, 0.0f)*dist) : 0.0f;
            r_lds[s] = 1.0f/(1.0f + expf(-rr));
            g_lds[s] = 1.0f/(1.0f + expf(-gg));
            b_lds[s] = 1.0f/(1.0f + expf(-bb));
        }
    }
    __syncthreads();

    // coalesced alpha output (zeros for dead range)
    for (int s = tid; s < NT; s += 256)
        out_alpha[(size_t)ray*NT + s] = (s < n_proc) ? a_lds[s] : 0.0f;

    // ---- phase 2: per-thread 3 consecutive samples ----
    float a_r[3], q_r[3], t_r[3], rr_r[3], gg_r[3], bb_r[3];
    #pragma unroll
    for (int k = 0; k < 3; ++k) {
        const int s = tid*3 + k;
        float a = 0.0f, rr = 0.0f, gg = 0.0f, bb = 0.0f, tt = 0.0f;
        if (s < NT) {
            tt = fminf(start + (float)(s+1)*INV127, stop);
            if (s < n_proc) {
                a = a_lds[s];
                rr = r_lds[s]; gg = g_lds[s]; bb = b_lds[s];
            }
        }
        a_r[k] = a; q_r[k] = (s < NT) ? (1.0f - a + EPSC) : 1.0f;
        t_r[k] = tt; rr_r[k] = rr; gg_r[k] = gg; bb_r[k] = bb;
    }

    // ---- block-wide exclusive product scan ----
    const float P = q_r[0]*q_r[1]*q_r[2];
    float incl = P;
    #pragma unroll
    for (int off2 = 1; off2 < 64; off2 <<= 1) {
        const float n = __shfl_up(incl, off2, 64);
        if (lane >= off2) incl *= n;
    }
    float excl = __shfl_up(incl, 1, 64);
    if (lane == 0) excl = 1.0f;

    if (lane == 63) wprod[wave] = incl;
    __syncthreads();
    float wpre = 1.0f;
    for (int w2 = 0; w2 < 4; ++w2) if (w2 < wave) wpre *= wprod[w2];

    // ---- phase 3: weighted accumulation ----
    float cum = wpre * excl;
    float accA = 0.0f, accR = 0.0f, accG = 0.0f, accB = 0.0f, accD = 0.0f;
    #pragma unroll
    for (int k = 0; k < 3; ++k) {
        const float abs_l = a_r[k] * cum;
        accA += abs_l;
        accR += abs_l * rr_r[k];
        accG += abs_l * gg_r[k];
        accB += abs_l * bb_r[k];
        accD += abs_l * t_r[k];
        cum *= q_r[k];
    }

    #pragma unroll
    for (int off2 = 32; off2 > 0; off2 >>= 1) {
        accA += __shfl_down(accA, off2, 64);
        accR += __shfl_down(accR, off2, 64);
        accG += __shfl_down(accG, off2, 64);
        accB += __shfl_down(accB, off2, 64);
        accD += __shfl_down(accD, off2, 64);
    }
    if (lane == 0) {
        red[wave][0] = accA; red[wave][1] = accR; red[wave][2] = accG;
        red[wave][3] = accB; red[wave][4] = accD;
    }
    __syncthreads();
    if (tid == 0) {
        float A = 0.0f, R = 0.0f, G = 0.0f, Bv = 0.0f, D = 0.0f;
        #pragma unroll
        for (int w2 = 0; w2 < 4; ++w2) {
            A += red[w2][0]; R += red[w2][1]; G += red[w2][2];
            Bv += red[w2][3]; D += red[w2][4];
        }
        const float bg = 1.0f - A;
        out_rgb[ray*3+0] = R  + bg;
        out_rgb[ray*3+1] = G  + bg;
        out_rgb[ray*3+2] = Bv + bg;
        out_depth[ray] = D;
    }
}

extern "C" void kernel_launch(void* const* d_in, const int* in_sizes, int n_in,
                              void* d_out, int out_size, void* d_ws, size_t ws_size,
                              hipStream_t stream) {
    const float* rays_d = (const float*)d_in[0];
    const float* rays_o = (const float*)d_in[1];
    const float* grid   = (const float*)d_in[2];
    const int B = in_sizes[0] / 3;   // 4096

    float* out       = (float*)d_out;
    float* out_rgb   = out;
    float* out_alpha = out + (size_t)B*3;
    float* out_depth = out + (size_t)B*3 + (size_t)B*NT;

    int* perm = (int*)d_ws;

    prep_sort<<<1, 1024, 0, stream>>>(rays_d, perm, B);
    nerf_grid_kernel<<<B, 256, 0, stream>>>(rays_d, rays_o, grid, perm,
                                            out_rgb, out_alpha, out_depth);
}

// Round 5
// 83.330 us; speedup vs baseline: 1.5859x; 1.0722x over previous
//
#include <hip/hip_runtime.h>
#include <math.h>

#define RESG 128
#define CHG 28
#define NT 767
#define NLBKT 48   // length buckets (n_proc >> 4)

template <int PAT>
static __device__ __forceinline__ float swz(float x) {
    return __int_as_float(__builtin_amdgcn_ds_swizzle(__float_as_int(x), PAT));
}

// ---------- prep: sort rays by live-length, DESCENDING ----------
__global__ __launch_bounds__(1024) void prep_sort(
    const float* __restrict__ rays_d, const float* __restrict__ rays_o,
    int* __restrict__ perm, int B)
{
    __shared__ int cnt[64];
    __shared__ int off[64];
    __shared__ unsigned char keys[4096];
    const int tid = threadIdx.x;
    if (tid < 64) cnt[tid] = 0;
    __syncthreads();
    for (int r = tid; r < B; r += 1024) {
        const float ox = rays_o[r*3+0], oy = rays_o[r*3+1], oz = rays_o[r*3+2];
        const float dx = rays_d[r*3+0], dy = rays_d[r*3+1], dz = rays_d[r*3+2];
        float txp = (1.0f - ox)/dx, txn = (-1.0f - ox)/dx;
        float typ = (1.0f - oy)/dy, tyn = (-1.0f - oy)/dy;
        float tzp = (1.0f - oz)/dz, tzn = (-1.0f - oz)/dz;
        const float start = fmaxf(fmaxf(fminf(txp,txn), fminf(typ,tyn)), fminf(tzp,tzn));
        const float stop  = fminf(fminf(fmaxf(txp,txn), fmaxf(typ,tyn)), fmaxf(tzp,tzn));
        int n_proc = (int)((stop - start) * 127.0f) + 2;
        n_proc = n_proc < 0 ? 0 : (n_proc > NT ? NT : n_proc);
        int lvl = n_proc >> 4; if (lvl > NLBKT-1) lvl = NLBKT-1;
        const int k = (NLBKT-1) - lvl;            // descending length
        keys[r] = (unsigned char)k;
        atomicAdd(&cnt[k], 1);
    }
    __syncthreads();
    if (tid < 64) {   // exclusive scan by wave 0
        int v = cnt[tid];
        int incl = v;
        #pragma unroll
        for (int o2 = 1; o2 < 64; o2 <<= 1) {
            const int n = __shfl_up(incl, o2, 64);
            if ((tid & 63) >= o2) incl += n;
        }
        off[tid] = incl - v;
    }
    __syncthreads();
    for (int r = tid; r < B; r += 1024) {
        const int slot = atomicAdd(&off[keys[r]], 1);
        perm[slot] = r;
    }
}

// ---------- main ----------
__global__ __launch_bounds__(256) void nerf_grid_kernel(
    const float* __restrict__ rays_d,
    const float* __restrict__ rays_o,
    const float* __restrict__ grid,     // [128^3][28] f32
    const int*   __restrict__ perm,
    float* __restrict__ out_rgb,
    float* __restrict__ out_alpha,
    float* __restrict__ out_depth)
{
    const int ray  = perm[blockIdx.x];
    const int tid  = threadIdx.x;
    const int lane = tid & 63;
    const int wave = tid >> 6;

    const float EPSC   = 1e-10f;
    const float INV127 = 1.0f / 127.0f;

    __shared__ float a_lds[NT + 1];
    __shared__ float r_lds[NT + 1];
    __shared__ float g_lds[NT + 1];
    __shared__ float b_lds[NT + 1];
    __shared__ float wprod[4];
    __shared__ float red[4][5];

    // ---- per-ray setup ----
    const float ox = rays_o[ray*3+0], oy = rays_o[ray*3+1], oz = rays_o[ray*3+2];
    const float dx = rays_d[ray*3+0], dy = rays_d[ray*3+1], dz = rays_d[ray*3+2];
    const float dnorm = sqrtf(dx*dx + dy*dy + dz*dz);

    float txp = (1.0f - ox)/dx, txn = (-1.0f - ox)/dx;
    float typ = (1.0f - oy)/dy, tyn = (-1.0f - oy)/dy;
    float tzp = (1.0f - oz)/dz, tzn = (-1.0f - oz)/dz;
    const float start = fmaxf(fmaxf(fminf(txp,txn), fminf(typ,tyn)), fminf(tzp,tzn));
    const float stop  = fminf(fminf(fmaxf(txp,txn), fmaxf(typ,tyn)), fmaxf(tzp,tzn));

    int n_proc = (int)((stop - start) * 127.0f) + 2;
    n_proc = n_proc < 0 ? 0 : (n_proc > NT ? NT : n_proc);

    // SH deg-2 basis
    const float inv = 1.0f/dnorm;
    const float nx = dx*inv, ny = dy*inv, nz = dz*inv;
    float sh0, sh1, sh2, sh3, sh4, sh5, sh6, sh7, sh8;
    {
        const float C0 = 0.28209479177387814f;
        const float C1 = 0.4886025119029199f;
        const float C20 = 1.0925484305920792f, C21 = -1.0925484305920792f;
        const float C22 = 0.31539156525252005f;
        const float C23 = -1.0925484305920792f, C24 = 0.5462742152960396f;
        sh0 = C0;   sh1 = -C1*ny; sh2 = C1*nz; sh3 = -C1*nx;
        sh4 = C20*nx*ny; sh5 = C21*ny*nz;
        sh6 = C22*(2.0f*nz*nz - nx*nx - ny*ny);
        sh7 = C23*nx*nz; sh8 = C24*(nx*nx - ny*ny);
    }

    // ---- phase 1: lane-per-corner gather; wave handles 8 consecutive samples ----
    const int samp   = lane >> 3;     // 0..7
    const int corner = lane & 7;      // bit0=dx, bit1=dy, bit2=dz
    const int cdx = corner & 1, cdy = (corner >> 1) & 1, cdz = corner >> 2;

    for (int base = wave*8; base < n_proc; base += 32) {
        const int s = base + samp;
        float rr = 0.0f, gg = 0.0f, bb = 0.0f, sg = 0.0f;
        float t0 = 0.0f, dist = 0.0f;
        bool live = false;
        if (s < n_proc) {
            t0 = fminf(start + (float)(s+1)*INV127, stop);
            const float t1 = fminf(start + (float)(s+2)*INV127, stop);
            dist = (t1 - t0) * dnorm;
            live = dist > 0.0f;
        }
        if (live) {
            const float gx = (ox + t0*dx + 1.0f)*63.5f;
            const float gy = (oy + t0*dy + 1.0f)*63.5f;
            const float gz = (oz + t0*dz + 1.0f)*63.5f;
            const float fx0 = floorf(gx), fy0 = floorf(gy), fz0 = floorf(gz);
            const float fx = gx - fx0, fy = gy - fy0, fz = gz - fz0;
            const int xi = (int)fx0 + cdx;
            const int yi = (int)fy0 + cdy;
            const int zi = (int)fz0 + cdz;
            const bool valid = ((unsigned)xi < (unsigned)RESG) &
                               ((unsigned)yi < (unsigned)RESG) &
                               ((unsigned)zi < (unsigned)RESG);
            const float w = (cdx ? fx : 1.0f-fx) *
                            (cdy ? fy : 1.0f-fy) *
                            (cdz ? fz : 1.0f-fz);
            if (valid && w != 0.0f) {
                const float4* row = (const float4*)(grid + (size_t)(((zi*RESG) + yi)*RESG + xi)*CHG);
                const float4 v0 = row[0], v1 = row[1], v2 = row[2], v3 = row[3];
                const float4 v4 = row[4], v5 = row[5], v6 = row[6];
                rr = w*(v0.x*sh0 + v0.y*sh1 + v0.z*sh2 + v0.w*sh3 +
                        v1.x*sh4 + v1.y*sh5 + v1.z*sh6 + v1.w*sh7 + v2.x*sh8);
                gg = w*(v2.y*sh0 + v2.z*sh1 + v2.w*sh2 + v3.x*sh3 +
                        v3.y*sh4 + v3.z*sh5 + v3.w*sh6 + v4.x*sh7 + v4.y*sh8);
                bb = w*(v4.z*sh0 + v4.w*sh1 + v5.x*sh2 + v5.y*sh3 +
                        v5.z*sh4 + v5.w*sh5 + v6.x*sh6 + v6.y*sh7 + v6.z*sh8);
                sg = w*v6.w;
            }
        }
        // reduce over the 8 corner lanes via immediate ds_swizzle (xor 1,2,4)
        rr += swz<0x041F>(rr); gg += swz<0x041F>(gg); bb += swz<0x041F>(bb); sg += swz<0x041F>(sg);
        rr += swz<0x081F>(rr); gg += swz<0x081F>(gg); bb += swz<0x081F>(bb); sg += swz<0x081F>(sg);
        rr += swz<0x101F>(rr); gg += swz<0x101F>(gg); bb += swz<0x101F>(bb); sg += swz<0x101F>(sg);

        if (corner == 0 && s < n_proc) {
            a_lds[s] = live ? 1.0f - expf(-fmaxf(sg, 0.0f)*dist) : 0.0f;
            r_lds[s] = 1.0f/(1.0f + expf(-rr));
            g_lds[s] = 1.0f/(1.0f + expf(-gg));
            b_lds[s] = 1.0f/(1.0f + expf(-bb));
        }
    }
    __syncthreads();

    // coalesced alpha output (zeros for dead range)
    for (int s = tid; s < NT; s += 256)
        out_alpha[(size_t)ray*NT + s] = (s < n_proc) ? a_lds[s] : 0.0f;

    // ---- phase 2: per-thread 3 consecutive samples ----
    float a_r[3], q_r[3], t_r[3], rr_r[3], gg_r[3], bb_r[3];
    #pragma unroll
    for (int k = 0; k < 3; ++k) {
        const int s = tid*3 + k;
        float a = 0.0f, rr = 0.0f, gg = 0.0f, bb = 0.0f, tt = 0.0f;
        if (s < NT) {
            tt = fminf(start + (float)(s+1)*INV127, stop);
            if (s < n_proc) {
                a = a_lds[s];
                rr = r_lds[s]; gg = g_lds[s]; bb = b_lds[s];
            }
        }
        a_r[k] = a; q_r[k] = (s < NT) ? (1.0f - a + EPSC) : 1.0f;
        t_r[k] = tt; rr_r[k] = rr; gg_r[k] = gg; bb_r[k] = bb;
    }

    // ---- block-wide exclusive product scan ----
    const float P = q_r[0]*q_r[1]*q_r[2];
    float incl = P;
    #pragma unroll
    for (int off2 = 1; off2 < 64; off2 <<= 1) {
        const float n = __shfl_up(incl, off2, 64);
        if (lane >= off2) incl *= n;
    }
    float excl = __shfl_up(incl, 1, 64);
    if (lane == 0) excl = 1.0f;

    if (lane == 63) wprod[wave] = incl;
    __syncthreads();
    float wpre = 1.0f;
    for (int w2 = 0; w2 < 4; ++w2) if (w2 < wave) wpre *= wprod[w2];

    // ---- phase 3: weighted accumulation ----
    float cum = wpre * excl;
    float accA = 0.0f, accR = 0.0f, accG = 0.0f, accB = 0.0f, accD = 0.0f;
    #pragma unroll
    for (int k = 0; k < 3; ++k) {
        const float abs_l = a_r[k] * cum;
        accA += abs_l;
        accR += abs_l * rr_r[k];
        accG += abs_l * gg_r[k];
        accB += abs_l * bb_r[k];
        accD += abs_l * t_r[k];
        cum *= q_r[k];
    }

    #pragma unroll
    for (int off2 = 32; off2 > 0; off2 >>= 1) {
        accA += __shfl_down(accA, off2, 64);
        accR += __shfl_down(accR, off2, 64);
        accG += __shfl_down(accG, off2, 64);
        accB += __shfl_down(accB, off2, 64);
        accD += __shfl_down(accD, off2, 64);
    }
    if (lane == 0) {
        red[wave][0] = accA; red[wave][1] = accR; red[wave][2] = accG;
        red[wave][3] = accB; red[wave][4] = accD;
    }
    __syncthreads();
    if (tid == 0) {
        float A = 0.0f, R = 0.0f, G = 0.0f, Bv = 0.0f, D = 0.0f;
        #pragma unroll
        for (int w2 = 0; w2 < 4; ++w2) {
            A += red[w2][0]; R += red[w2][1]; G += red[w2][2];
            Bv += red[w2][3]; D += red[w2][4];
        }
        const float bg = 1.0f - A;
        out_rgb[ray*3+0] = R  + bg;
        out_rgb[ray*3+1] = G  + bg;
        out_rgb[ray*3+2] = Bv + bg;
        out_depth[ray] = D;
    }
}

extern "C" void kernel_launch(void* const* d_in, const int* in_sizes, int n_in,
                              void* d_out, int out_size, void* d_ws, size_t ws_size,
                              hipStream_t stream) {
    const float* rays_d = (const float*)d_in[0];
    const float* rays_o = (const float*)d_in[1];
    const float* grid   = (const float*)d_in[2];
    const int B = in_sizes[0] / 3;   // 4096

    float* out       = (float*)d_out;
    float* out_rgb   = out;
    float* out_alpha = out + (size_t)B*3;
    float* out_depth = out + (size_t)B*3 + (size_t)B*NT;

    int* perm = (int*)d_ws;

    prep_sort<<<1, 1024, 0, stream>>>(rays_d, rays_o, perm, B);
    nerf_grid_kernel<<<B, 256, 0, stream>>>(rays_d, rays_o, grid, perm,
                                            out_rgb, out_alpha, out_depth);
}